// Round 10
// baseline (110.996 us; speedup 1.0000x reference)
//
#include <hip/hip_runtime.h>
#include <hip/hip_bf16.h>
#include <stdint.h>

#define NB 8
#define DIMG 2048
#define HWN 196
#define PN 1568
#define PPAD 1600
#define DMID 1024
#define NC 80
#define DWORD 300
#define PART 16

typedef short bf16x8 __attribute__((ext_vector_type(8)));
typedef float f32x4 __attribute__((ext_vector_type(4)));

__device__ __forceinline__ unsigned short f2bf(float x) {
  union { float f; unsigned u; } c; c.f = x;
  unsigned r = c.u + 0x7FFFu + ((c.u >> 16) & 1u);
  return (unsigned short)(r >> 16);
}

// ---------------------------------------------------------------- transpose (bf16 only) + W1 cvt
__global__ void k_tc(const float* __restrict__ img, unsigned short* __restrict__ fmapH,
                     const float* __restrict__ W1, unsigned short* __restrict__ W1h) {
  __shared__ float tile[32][33];
  int bx = blockIdx.x;
  int tx = threadIdx.x, ty = threadIdx.y;
  if (bx < 3584) {
    int d0 = (bx & 63) * 32;
    int rem = bx >> 6;
    int h0 = (rem % 7) * 32, b = rem / 7;
    const float* src = img + (size_t)b * DIMG * HWN;
#pragma unroll
    for (int i = 0; i < 32; i += 8) {
      int hw = h0 + tx;
      tile[ty + i][tx] = (hw < HWN) ? src[(size_t)(d0 + ty + i) * HWN + hw] : 0.f;
    }
    __syncthreads();
#pragma unroll
    for (int i = 0; i < 32; i += 8) {
      int hw = h0 + ty + i;
      if (hw < HWN)
        fmapH[(size_t)(b * HWN + hw) * DIMG + d0 + tx] = f2bf(tile[tx][ty + i]);
    }
  } else {
    int tid = ty * 32 + tx;
    int i = ((bx - 3584) * 256 + tid) * 4;
    f32x4 v = *(const f32x4*)(W1 + i);
    ushort4 s;
    s.x = f2bf(v[0]); s.y = f2bf(v[1]); s.z = f2bf(v[2]); s.w = f2bf(v[3]);
    *(ushort4*)(W1h + i) = s;
  }
}

// ---------------------------------------------------------------- fwd + weff (coalesced, LDS-staged)
// fwd[c][m] = SC * sum_k word[c][k]*W2[m][k]  (SC = 2*log2e)
__global__ __launch_bounds__(256) void k_fwdweff(const float* __restrict__ word,
                                                 const float* __restrict__ W2,
                                                 float* __restrict__ fwd,
                                                 const float* __restrict__ Wa,
                                                 const float* __restrict__ W3,
                                                 float* __restrict__ partial) {
  __shared__ __align__(16) float w2s[64 * DWORD];   // 76.8 KB
  __shared__ __align__(16) float wds[16 * DWORD];   // 19.2 KB
  int bx = blockIdx.x, t = threadIdx.x;
  if (bx < 80) {
    int m0 = (bx & 15) * 64, c0 = (bx >> 4) * 16;
    const float SC = 2.8853900817779268f;  // 2*log2(e)
    for (int u = t; u < 64 * 75; u += 256) {
      int r = u / 75, q = u - r * 75;
      *(f32x4*)&w2s[r * DWORD + q * 4] =
          *(const f32x4*)(W2 + (size_t)(m0 + r) * DWORD + q * 4);
    }
    for (int u = t; u < 16 * 75; u += 256) {
      int r = u / 75, q = u - r * 75;
      f32x4 v = *(const f32x4*)(word + (size_t)(c0 + r) * DWORD + q * 4);
      *(f32x4*)&wds[r * DWORD + q * 4] = v * SC;
    }
    __syncthreads();
    int ci = t >> 4, mi = t & 15;
    f32x4 a0 = {0.f, 0.f, 0.f, 0.f}, a1 = a0, a2 = a0, a3 = a0;
    const float* wr = &wds[ci * DWORD];
    for (int q = 0; q < 75; ++q) {
      f32x4 wv = *(const f32x4*)&wr[q * 4];
      f32x4 b0 = *(const f32x4*)&w2s[(mi)*DWORD + q * 4];
      f32x4 b1 = *(const f32x4*)&w2s[(mi + 16) * DWORD + q * 4];
      f32x4 b2 = *(const f32x4*)&w2s[(mi + 32) * DWORD + q * 4];
      f32x4 b3 = *(const f32x4*)&w2s[(mi + 48) * DWORD + q * 4];
#pragma unroll
      for (int u = 0; u < 4; ++u) {
        a0[u] = fmaf(wv[u], b0[u], a0[u]);
        a1[u] = fmaf(wv[u], b1[u], a1[u]);
        a2[u] = fmaf(wv[u], b2[u], a2[u]);
        a3[u] = fmaf(wv[u], b3[u], a3[u]);
      }
    }
    float* dst = fwd + (size_t)(c0 + ci) * DMID + m0 + mi;
    dst[0]  = a0[0] + a0[1] + a0[2] + a0[3];
    dst[16] = a1[0] + a1[1] + a1[2] + a1[3];
    dst[32] = a2[0] + a2[1] + a2[2] + a2[3];
    dst[48] = a3[0] + a3[1] + a3[2] + a3[3];
  } else {
    int idx = bx - 80;
    int m = (idx & 3) * 256 + t;
    int n0 = (idx >> 2) * 64;
    float acc = 0.f;
    for (int n = n0; n < n0 + 64; ++n) acc = fmaf(Wa[n], W3[(size_t)n * DMID + m], acc);
    partial[(size_t)(idx >> 2) * DMID + m] = acc;
  }
}

// ---------------------------------------------------------------- FUSED: MFMA X-tile [32p][64m] + sigmoid-sum
// grid (50, 16): block (px, mz). 36 KB LDS union -> 4 blocks/CU; cross-block MFMA/VALU overlap.
#define GLDS(g, l) \
  __builtin_amdgcn_global_load_lds((const __attribute__((address_space(1))) void*)(g), \
                                   (__attribute__((address_space(3))) void*)(l), 16, 0, 0)

__global__ __launch_bounds__(256) void k_fused(const unsigned short* __restrict__ A,
                                               const unsigned short* __restrict__ Bw,
                                               const float* __restrict__ fwd,
                                               const float* __restrict__ partial,
                                               float* __restrict__ coefp) {
  __shared__ __align__(16) char smem[36864];           // union: 36 KB
  unsigned short* As = (unsigned short*)smem;          // [3][32*64] ushort (12 KB)
  unsigned short* Bs = As + 3 * 2048;                  // [3][64*64] ushort (24 KB)
  float* Xl = (float*)smem;                            // [32][68] f32 ( 8.7 KB)
  float* bl = Xl + 32 * 68;                            // [80][68] f32 (21.8 KB)
  float* wl = bl + 80 * 68;                            // [64] f32
  int p0 = blockIdx.x * 32, mz = blockIdx.y;
  int n0 = mz * 64;
  int t = threadIdx.x;
  int w = t >> 6, l = t & 63;
  f32x4 zero = {0.f, 0.f, 0.f, 0.f};
  f32x4 acc0 = zero, acc1 = zero;   // p 0-15 / 16-31 of wave's 16-m slice

  // staging: A 32x64 = 256 chunks (1/thread), B 64x64 = 512 chunks (2/thread)
  int r0 = t >> 3, cch = t & 7;
  int r1 = r0 + 32;
  const unsigned short* ga0 = A + (size_t)(p0 + r0) * 2048 + ((cch ^ (r0 & 7)) << 3);
  const unsigned short* gb0 = Bw + (size_t)(n0 + r0) * 2048 + ((cch ^ (r0 & 7)) << 3);
  const unsigned short* gb1 = Bw + (size_t)(n0 + r1) * 2048 + ((cch ^ (r1 & 7)) << 3);

  // frag offsets: A rows ra, ra+16; B rows w*16 + (l&15); k-chunk cc and cc+4
  int ra = l & 15;
  int rb = w * 16 + (l & 15);
  int cc = l >> 4;
  int a_k0 = ra * 64 + (((cc) ^ (ra & 7)) << 3);
  int a_k1 = ra * 64 + (((cc + 4) ^ (ra & 7)) << 3);
  int b_k0 = rb * 64 + (((cc) ^ (rb & 7)) << 3);
  int b_k1 = rb * 64 + (((cc + 4) ^ (rb & 7)) << 3);

#define STAGE(bi, kk) do { \
    GLDS(ga0 + (kk), As + (bi) * 2048 + t * 8); \
    GLDS(gb0 + (kk), Bs + (bi) * 4096 + t * 8); \
    GLDS(gb1 + (kk), Bs + (bi) * 4096 + t * 8 + 2048); \
  } while (0)

#define COMPUTE(bi) do { \
    const unsigned short* ap = As + (bi) * 2048; \
    const unsigned short* bp = Bs + (bi) * 4096; \
    bf16x8 A0 = *(const bf16x8*)(ap + a_k0); \
    bf16x8 A1 = *(const bf16x8*)(ap + a_k0 + 1024); \
    bf16x8 B0 = *(const bf16x8*)(bp + b_k0); \
    __builtin_amdgcn_s_setprio(1); \
    acc0 = __builtin_amdgcn_mfma_f32_16x16x32_bf16(A0, B0, acc0, 0, 0, 0); \
    acc1 = __builtin_amdgcn_mfma_f32_16x16x32_bf16(A1, B0, acc1, 0, 0, 0); \
    __builtin_amdgcn_s_setprio(0); \
    bf16x8 A2 = *(const bf16x8*)(ap + a_k1); \
    bf16x8 A3 = *(const bf16x8*)(ap + a_k1 + 1024); \
    bf16x8 B1 = *(const bf16x8*)(bp + b_k1); \
    __builtin_amdgcn_s_setprio(1); \
    acc0 = __builtin_amdgcn_mfma_f32_16x16x32_bf16(A2, B1, acc0, 0, 0, 0); \
    acc1 = __builtin_amdgcn_mfma_f32_16x16x32_bf16(A3, B1, acc1, 0, 0, 0); \
    __builtin_amdgcn_s_setprio(0); \
  } while (0)

  STAGE(0, 0);
  STAGE(1, 64);
  asm volatile("s_waitcnt vmcnt(3)" ::: "memory");
  __builtin_amdgcn_s_barrier();
  __builtin_amdgcn_sched_barrier(0);
  for (int kt = 0; kt < 32; ++kt) {
    int cur = kt % 3;
    if (kt < 30) STAGE((kt + 2) % 3, (kt + 2) * 64);
    COMPUTE(cur);
    if (kt < 30) {
      asm volatile("s_waitcnt vmcnt(3)" ::: "memory");
      __builtin_amdgcn_s_barrier();
      __builtin_amdgcn_sched_barrier(0);
    } else if (kt == 30) {
      asm volatile("s_waitcnt vmcnt(0)" ::: "memory");
      __builtin_amdgcn_s_barrier();
      __builtin_amdgcn_sched_barrier(0);
    }
  }
  __syncthreads();   // all waves done with As/Bs -> safe to overwrite union

  // write X tile [32][68]: wave w's cols w*16..+15; rows (l>>4)*4+q (+16)
  {
    int xr = (l >> 4) << 2, xc = w * 16 + (l & 15);
#pragma unroll
    for (int q = 0; q < 4; ++q) {
      Xl[(xr + q) * 68 + xc]        = acc0[q];
      Xl[(xr + q + 16) * 68 + xc]   = acc1[q];
    }
    // stage fwd slice [80][64] (prescaled) and wl[m] = -2*sum_s partial
#pragma unroll
    for (int i = 0; i < 5; ++i) {
      int idx = t + 256 * i;
      int r = idx >> 4, c4 = (idx & 15) << 2;
      *(f32x4*)&bl[r * 68 + c4] = *(const f32x4*)(fwd + (size_t)r * DMID + n0 + c4);
    }
    if (t < 64) {
      float v = 0.f;
#pragma unroll
      for (int s = 0; s < 16; ++s) v += partial[(size_t)s * DMID + n0 + t];
      wl[t] = -2.f * v;
    }
  }
  __syncthreads();

  // sigmoid-sum: m-outer, c-inner; acc[2 p-reps][5 c-chunks]
  int pi = t >> 4, ci = t & 15;
  float acc[2][5];
#pragma unroll
  for (int j = 0; j < 2; ++j)
#pragma unroll
    for (int k = 0; k < 5; ++k) acc[j][k] = 0.f;

#pragma unroll 1
  for (int mm = 0; mm < 64; mm += 4) {
    f32x4 wv = *(const f32x4*)&wl[mm];
    f32x4 av0 = *(const f32x4*)&Xl[(pi)*68 + mm];
    f32x4 av1 = *(const f32x4*)&Xl[(pi + 16) * 68 + mm];
#pragma unroll
    for (int k = 0; k < 5; ++k) {
      f32x4 bv = *(const f32x4*)&bl[(k * 16 + ci) * 68 + mm];
#pragma unroll
      for (int u = 0; u < 4; ++u) {
        float wgt = wv[u], b = bv[u];
        float e0 = __builtin_amdgcn_exp2f(av0[u] * b);
        float e1 = __builtin_amdgcn_exp2f(av1[u] * b);
        acc[0][k] = fmaf(wgt, __builtin_amdgcn_rcpf(1.f + e0), acc[0][k]);
        acc[1][k] = fmaf(wgt, __builtin_amdgcn_rcpf(1.f + e1), acc[1][k]);
      }
    }
  }
  float* cp = coefp + (size_t)mz * (PN * NC);
#pragma unroll
  for (int j = 0; j < 2; ++j) {
    int p = p0 + pi + 16 * j;
    if (p < PN) {
#pragma unroll
      for (int k = 0; k < 5; ++k)
        cp[(size_t)p * NC + k * 16 + ci] = acc[j][k];
    }
  }
#undef STAGE
#undef COMPUTE
}

// ---------------------------------------------------------------- softmax + pooling; reads img directly
__global__ __launch_bounds__(256) void k_pool(const float* __restrict__ coefp,
                                              const float* __restrict__ img,
                                              float* __restrict__ out) {
  __shared__ __align__(16) float wt[HWN][16];
  __shared__ float red[16][16];
  __shared__ float mxs[16], inv[16];
  int dc = blockIdx.x * 256, cg = blockIdx.y * 16, b = blockIdx.z;
  int t = threadIdx.x;
  for (int i = t; i < HWN * 4; i += 256) {
    int hw = i >> 2, j4 = (i & 3) << 2;
    size_t o = (size_t)(b * HWN + hw) * NC + cg + j4;
    f32x4 s = {0.f, 0.f, 0.f, 0.f};
#pragma unroll
    for (int z = 0; z < PART; ++z) s += *(const f32x4*)&coefp[o + (size_t)z * (PN * NC)];
    *(f32x4*)&wt[hw][j4] = s;
  }
  __syncthreads();
  int j = t & 15, g = t >> 4;
  float pm = -1e30f;
  for (int hw = g; hw < HWN; hw += 16) pm = fmaxf(pm, wt[hw][j]);
  red[g][j] = pm;
  __syncthreads();
  if (t < 16) {
    float m = red[0][t];
#pragma unroll
    for (int g2 = 1; g2 < 16; ++g2) m = fmaxf(m, red[g2][t]);
    mxs[t] = m;
  }
  __syncthreads();
  float mj = mxs[j], ps = 0.f;
  for (int hw = g; hw < HWN; hw += 16) {
    float e = __builtin_amdgcn_exp2f((wt[hw][j] - mj) * 1.4426950408889634f);
    wt[hw][j] = e;
    ps += e;
  }
  red[g][j] = ps;
  __syncthreads();
  if (t < 16) {
    float s = 0.f;
#pragma unroll
    for (int g2 = 0; g2 < 16; ++g2) s += red[g2][t];
    inv[t] = 1.f / s;
  }
  __syncthreads();
  float acc[16];
#pragma unroll
  for (int q = 0; q < 16; ++q) acc[q] = 0.f;
  const float* fpd = img + ((size_t)b * DIMG + dc + t) * HWN;
  for (int hw = 0; hw < HWN; ++hw) {
    float v = fpd[hw];
#pragma unroll
    for (int q = 0; q < 16; ++q) acc[q] = fmaf(wt[hw][q], v, acc[q]);
  }
#pragma unroll
  for (int q = 0; q < 16; ++q)
    out[((size_t)b * NC + cg + q) * DIMG + dc + t] = acc[q] * inv[q];
}

// ----------------------------------------------------------------
extern "C" void kernel_launch(void* const* d_in, const int* in_sizes, int n_in,
                              void* d_out, int out_size, void* d_ws, size_t ws_size,
                              hipStream_t stream) {
  const float* img  = (const float*)d_in[1];
  const float* word = (const float*)d_in[2];
  const float* W1   = (const float*)d_in[3];
  const float* W2   = (const float*)d_in[4];
  const float* W3   = (const float*)d_in[5];
  const float* Wa   = (const float*)d_in[7];
  // b3 (d_in[6]) and ba (d_in[8]) are softmax-shift-invariant -> dropped.
  float* out = (float*)d_out;
  char* ws = (char*)d_ws;

  unsigned short* fmapH   = (unsigned short*)(ws + 0);         // 1600*2048*2 = 6,553,600
  unsigned short* W1h     = (unsigned short*)(ws + 6553600);   // 1024*2048*2 = 4,194,304
  float*          fwd     = (float*)(ws + 10747904);           //  96*1024*4 =   393,216
  float*          partial = (float*)(ws + 11141120);           //  16*1024*4 =    65,536
  float*          coefp   = (float*)(ws + 11206656);           // 16*1568*80*4 = 8,028,160

  hipLaunchKernelGGL(k_tc, dim3(5632), dim3(32, 8), 0, stream, img, fmapH, W1, W1h);
  hipLaunchKernelGGL(k_fwdweff, dim3(144), dim3(256), 0, stream,
                     word, W2, fwd, Wa, W3, partial);
  hipLaunchKernelGGL(k_fused, dim3(50, 16), dim3(256), 0, stream,
                     fmapH, W1h, fwd, partial, coefp);
  hipLaunchKernelGGL(k_pool, dim3(8, 5, 8), dim3(256), 0, stream, coefp, img, out);
  (void)in_sizes; (void)n_in; (void)out_size; (void)ws_size;
}